// Round 1
// baseline (975.472 us; speedup 1.0000x reference)
//
#include <hip/hip_runtime.h>
#include <hip/hip_bf16.h>

#define NN 16384
#define DD 128
#define BM 64
#define BK 64
#define NT (NN / BK)   // 256 K-tiles

typedef __attribute__((ext_vector_type(8))) short short8;
typedef __attribute__((ext_vector_type(4))) float f32x4;

__device__ __forceinline__ short f2bf(float f) {
  union { float f; unsigned u; } v; v.f = f;
  unsigned r = v.u + 0x7fffu + ((v.u >> 16) & 1u);   // RNE f32->bf16
  return (short)(r >> 16);
}
__device__ __forceinline__ float bf2f(short s) {
  union { unsigned u; float f; } v; v.u = ((unsigned)(unsigned short)s) << 16;
  return v.f;
}
// swizzled byte offset within a [rows][BK] bf16 K-major LDS tile (row pitch 128B)
__device__ __forceinline__ int swzo(int row, int byteCol) {
  return (row * (BK * 2) + byteCol) ^ ((row & 7) << 4);
}

// ---------------------------------------------------------------------------
// small GEMM: Tt[d][k] = sum_j In[k][j] * W[j][d]   (writes bf16, K-major/transposed)
// In: [16384][128] fp32 (layer 0) or bf16 (layer 1). W: [128][128] fp32.
// grid = 1024 blocks x 256 thr; each block does 16 k-rows.
// ---------------------------------------------------------------------------
template<int IN_BF16>
__global__ __launch_bounds__(256, 1)
void small_gemm(const void* __restrict__ In_, const float* __restrict__ W,
                short* __restrict__ Tt)
{
  __shared__ float sW[DD * DD];   // 64 KB
  const int tid = threadIdx.x;
  {
    const float4* W4 = (const float4*)W;
    float4* sW4 = (float4*)sW;
#pragma unroll
    for (int i = 0; i < 16; ++i) sW4[tid + 256 * i] = W4[tid + 256 * i];
  }
  __syncthreads();

  const int k0 = blockIdx.x * 16;
  const int k  = tid & 15;        // k-row within tile
  const int q  = tid >> 4;        // d-chunk 0..15 -> d = 8q..8q+7
  const long rowoff = (long)(k0 + k) * DD;

  float acc[8] = {0.f, 0.f, 0.f, 0.f, 0.f, 0.f, 0.f, 0.f};
  for (int j = 0; j < DD; ++j) {
    float a;
    if (IN_BF16) a = bf2f(((const short*)In_)[rowoff + j]);
    else         a = ((const float*)In_)[rowoff + j];
#pragma unroll
    for (int dd = 0; dd < 8; ++dd)
      acc[dd] += a * sW[j * DD + q * 8 + dd];
  }
  // NO relu here (relu comes after the aggregation)
#pragma unroll
  for (int dd = 0; dd < 8; ++dd)
    Tt[(long)(q * 8 + dd) * NN + k0 + k] = f2bf(acc[dd]);
}

// ---------------------------------------------------------------------------
// aggregation: Out = relu(A @ T), with T given K-major as Tt[d][k] (bf16).
// A fp32 [16384][16384] converted to bf16 on the fly. MFMA 16x16x32 bf16.
// block: 64 rows x 128 cols, 4 waves (2x2 of 32x64), BK=64, LDS double-buffer.
// ---------------------------------------------------------------------------
template<int WRITE_BF16>
__global__ __launch_bounds__(256, 1)
void agg_kernel(const float* __restrict__ A, const short* __restrict__ Bt,
                void* __restrict__ out_)
{
  __shared__ __align__(16) short sA[2][BM * BK];   // 8 KB each, swizzled
  __shared__ __align__(16) short sB[2][DD * BK];   // 16 KB each, swizzled

  const int tid  = threadIdx.x;
  const int lane = tid & 63;
  const int w    = tid >> 6;
  const int wm   = w >> 1;          // wave row 0..1  (32 rows each)
  const int wn   = w & 1;           // wave col 0..1  (64 cols each)
  const long gm0 = (long)blockIdx.x * BM;

  const int ar  = tid >> 4;         // A staging: row 0..15 (+16p)
  const int akf = (tid & 15) << 2;  // A staging: float col 0..60
  const int bd  = tid >> 3;         // B staging: d 0..31 (+32p)
  const int bxc = (tid & 7) << 3;   // B staging: bf16 col 0..56

  f32x4 acc[2][4];
#pragma unroll
  for (int i = 0; i < 2; ++i)
#pragma unroll
    for (int j = 0; j < 4; ++j) acc[i][j] = (f32x4){0.f, 0.f, 0.f, 0.f};

  float4 areg[4];
  uint4  breg[4];

  auto LOAD = [&](int t) {
    const long k0 = (long)t * BK;
#pragma unroll
    for (int p = 0; p < 4; ++p)
      areg[p] = *(const float4*)&A[(gm0 + ar + 16 * p) * NN + k0 + akf];
#pragma unroll
    for (int p = 0; p < 4; ++p)
      breg[p] = *(const uint4*)&Bt[(long)(bd + 32 * p) * NN + k0 + bxc];
  };

  auto STORE = [&](int buf) {
#pragma unroll
    for (int p = 0; p < 4; ++p) {
      const int r = ar + 16 * p;
      uint2 w2;
      w2.x = ((unsigned)(unsigned short)f2bf(areg[p].y) << 16) |
             (unsigned)(unsigned short)f2bf(areg[p].x);
      w2.y = ((unsigned)(unsigned short)f2bf(areg[p].w) << 16) |
             (unsigned)(unsigned short)f2bf(areg[p].z);
      *(uint2*)((char*)sA[buf] + swzo(r, akf * 2)) = w2;
    }
#pragma unroll
    for (int p = 0; p < 4; ++p) {
      const int d = bd + 32 * p;
      *(uint4*)((char*)sB[buf] + swzo(d, bxc * 2)) = breg[p];
    }
  };

  auto COMPUTE = [&](int buf) {
#pragma unroll
    for (int ks = 0; ks < 2; ++ks) {
      const int kb = ks * 64 + ((lane >> 4) << 4);  // byte col: (ks*32 + (lane>>4)*8)*2
      short8 afr[2], bfr[4];
#pragma unroll
      for (int i = 0; i < 2; ++i) {
        const int r = wm * 32 + i * 16 + (lane & 15);
        afr[i] = *(const short8*)((const char*)sA[buf] + swzo(r, kb));
      }
#pragma unroll
      for (int j = 0; j < 4; ++j) {
        const int d = wn * 64 + j * 16 + (lane & 15);
        bfr[j] = *(const short8*)((const char*)sB[buf] + swzo(d, kb));
      }
#pragma unroll
      for (int i = 0; i < 2; ++i)
#pragma unroll
        for (int j = 0; j < 4; ++j)
          acc[i][j] = __builtin_amdgcn_mfma_f32_16x16x32_bf16(
              afr[i], bfr[j], acc[i][j], 0, 0, 0);
    }
  };

  LOAD(0);
  STORE(0);
  __syncthreads();

  for (int t = 0; t < NT; t += 2) {
    // phase A: compute buf0 (tile t), prefetch tile t+1 -> buf1
    if (t + 1 < NT) LOAD(t + 1);
    COMPUTE(0);
    if (t + 1 < NT) STORE(1);
    __syncthreads();
    // phase B: compute buf1 (tile t+1), prefetch tile t+2 -> buf0
    if (t + 1 < NT) {
      if (t + 2 < NT) LOAD(t + 2);
      COMPUTE(1);
      if (t + 2 < NT) STORE(0);
      __syncthreads();
    }
  }

  // epilogue: relu + store (C layout: row = (lane>>4)*4 + reg, col = lane&15)
#pragma unroll
  for (int i = 0; i < 2; ++i) {
#pragma unroll
    for (int j = 0; j < 4; ++j) {
#pragma unroll
      for (int r = 0; r < 4; ++r) {
        float v = acc[i][j][r];
        v = v > 0.f ? v : 0.f;
        const long row = gm0 + wm * 32 + i * 16 + ((lane >> 4) << 2) + r;
        const int  col = wn * 64 + j * 16 + (lane & 15);
        if (WRITE_BF16) ((short*)out_)[row * DD + col] = f2bf(v);
        else            ((float*)out_)[row * DD + col] = v;
      }
    }
  }
}

// ---------------------------------------------------------------------------
extern "C" void kernel_launch(void* const* d_in, const int* in_sizes, int n_in,
                              void* d_out, int out_size, void* d_ws, size_t ws_size,
                              hipStream_t stream)
{
  const float* A  = (const float*)d_in[0];   // [16384][16384]
  const float* X  = (const float*)d_in[1];   // [16384][128]
  const float* W0 = (const float*)d_in[2];   // [128][128]
  const float* W1 = (const float*)d_in[3];   // [128][128]

  short* Tt = (short*)d_ws;                  // bf16 [128][16384] (K-major T)
  short* H1 = Tt + (size_t)DD * NN;          // bf16 [16384][128] (post-relu H1)

  // layer 0: T0 = X @ W0 ; H1 = relu(A @ T0)
  small_gemm<0><<<NN / 16, 256, 0, stream>>>(X, W0, Tt);
  agg_kernel<1><<<NN / BM, 256, 0, stream>>>(A, Tt, H1);
  // layer 1: T1 = H1 @ W1 ; out = relu(A @ T1)
  small_gemm<1><<<NN / 16, 256, 0, stream>>>(H1, W1, Tt);
  agg_kernel<0><<<NN / BM, 256, 0, stream>>>(A, Tt, d_out);
}

// Round 2
// 748.366 us; speedup vs baseline: 1.3035x; 1.3035x over previous
//
#include <hip/hip_runtime.h>
#include <hip/hip_bf16.h>

#define NN 16384
#define DD 128
#define BM 32
#define BK 128
#define NT (NN / BK)   // 128 K-tiles

typedef __attribute__((ext_vector_type(8))) short short8;
typedef __attribute__((ext_vector_type(4))) float f32x4;

__device__ __forceinline__ short f2bf(float f) {
  union { float f; unsigned u; } v; v.f = f;
  unsigned r = v.u + 0x7fffu + ((v.u >> 16) & 1u);   // RNE f32->bf16
  return (short)(r >> 16);
}
__device__ __forceinline__ float bf2f(short s) {
  union { unsigned u; float f; } v; v.u = ((unsigned)(unsigned short)s) << 16;
  return v.f;
}
__device__ __forceinline__ unsigned pk2(float a, float b) {
  return ((unsigned)(unsigned short)f2bf(b) << 16) | (unsigned)(unsigned short)f2bf(a);
}
// swizzled byte offset within a [rows][BK] bf16 K-major LDS tile (row pitch 256B)
__device__ __forceinline__ int swzo(int row, int byteCol) {
  return (row * (BK * 2) + byteCol) ^ ((row & 7) << 4);
}

// ---------------------------------------------------------------------------
// small GEMM: T = In @ W, written in MFMA B-fragment-major layout:
//   for element (d, k):  kt=k>>5, dt=d>>4, lane=(d&15)|(((k>>3)&3)<<4), e=k&7
//   Tf[(((kt*8)+dt)*64 + lane)*8 + e]
// In: [16384][128] fp32 (layer 0) or bf16 (layer 1). W: [128][128] fp32.
// ---------------------------------------------------------------------------
template<int IN_BF16>
__global__ __launch_bounds__(256, 1)
void small_gemm(const void* __restrict__ In_, const float* __restrict__ W,
                short* __restrict__ Tf)
{
  __shared__ float sW[DD * DD];   // 64 KB
  const int tid = threadIdx.x;
  {
    const float4* W4 = (const float4*)W;
    float4* sW4 = (float4*)sW;
#pragma unroll
    for (int i = 0; i < 16; ++i) sW4[tid + 256 * i] = W4[tid + 256 * i];
  }
  __syncthreads();

  const int k0 = blockIdx.x * 16;
  const int kk = tid & 15;        // k-row within tile
  const int q  = tid >> 4;        // d-chunk 0..15 -> d = 8q..8q+7
  const long rowoff = (long)(k0 + kk) * DD;

  float acc[8] = {0.f, 0.f, 0.f, 0.f, 0.f, 0.f, 0.f, 0.f};
  for (int j = 0; j < DD; ++j) {
    float a;
    if (IN_BF16) a = bf2f(((const short*)In_)[rowoff + j]);
    else         a = ((const float*)In_)[rowoff + j];
#pragma unroll
    for (int dd = 0; dd < 8; ++dd)
      acc[dd] += a * sW[j * DD + q * 8 + dd];
  }
  const int k    = k0 + kk;
  const int kt   = k >> 5;
  const int ksub = (k >> 3) & 3;
  const int e    = k & 7;
#pragma unroll
  for (int dd = 0; dd < 8; ++dd) {
    const int d  = q * 8 + dd;
    const int dt = d >> 4;
    const int lf = (d & 15) | (ksub << 4);
    Tf[((((long)kt * 8) + dt) * 64 + lf) * 8 + e] = f2bf(acc[dd]);
  }
}

// ---------------------------------------------------------------------------
// aggregation: Out = relu(A @ T), T given fragment-major (bf16).
// A fp32 [16384][16384] -> bf16 on the fly, staged in LDS (A only, 16 KB dbuf).
// block: 32 rows x 128 cols, 4 waves (each 32x32), BK=128, grid 512 = 2/CU.
// B-fragments read directly from global (L2/L3-hot, fully coalesced).
// ---------------------------------------------------------------------------
template<int WRITE_BF16>
__global__ __launch_bounds__(256, 2)
void agg_kernel(const float* __restrict__ A, const short* __restrict__ Bf,
                void* __restrict__ out_)
{
  __shared__ __align__(16) short sA[2][BM * BK];   // 8 KB each, swizzled

  const int tid  = threadIdx.x;
  const int lane = tid & 63;
  const int w    = tid >> 6;        // wave 0..3 -> cols w*32..w*32+31
  const long gm0 = (long)blockIdx.x * BM;

  const int ar  = tid >> 3;         // staging row 0..31
  const int acf = (tid & 7) << 4;   // staging float col (16 floats = 64B/thread)

  f32x4 acc[2][2];
#pragma unroll
  for (int i = 0; i < 2; ++i)
#pragma unroll
    for (int j = 0; j < 2; ++j) acc[i][j] = (f32x4){0.f, 0.f, 0.f, 0.f};

  float4 areg[4];

  auto LOAD = [&](int t) {
    const long base = (gm0 + ar) * NN + (long)t * BK + acf;
#pragma unroll
    for (int p = 0; p < 4; ++p)
      areg[p] = *(const float4*)&A[base + 4 * p];
  };

  auto STORE = [&](int buf) {
#pragma unroll
    for (int p2 = 0; p2 < 2; ++p2) {
      uint4 v;
      v.x = pk2(areg[2 * p2].x, areg[2 * p2].y);
      v.y = pk2(areg[2 * p2].z, areg[2 * p2].w);
      v.z = pk2(areg[2 * p2 + 1].x, areg[2 * p2 + 1].y);
      v.w = pk2(areg[2 * p2 + 1].z, areg[2 * p2 + 1].w);
      *(uint4*)((char*)sA[buf] + swzo(ar, (acf << 1) + (p2 << 4))) = v;
    }
  };

  auto COMPUTE = [&](int buf, int t) {
    short8 bfr[4][2];
#pragma unroll
    for (int ks = 0; ks < 4; ++ks)
#pragma unroll
      for (int j = 0; j < 2; ++j)
        bfr[ks][j] = *(const short8*)&Bf[((((long)(t * 4 + ks) * 8) +
                                          (w * 2 + j)) * 64 + lane) * 8];
#pragma unroll
    for (int ks = 0; ks < 4; ++ks) {
      const int kb = ks * 64 + ((lane >> 4) << 4);
      short8 afr[2];
#pragma unroll
      for (int i = 0; i < 2; ++i)
        afr[i] = *(const short8*)((const char*)sA[buf] +
                                  swzo(i * 16 + (lane & 15), kb));
#pragma unroll
      for (int i = 0; i < 2; ++i)
#pragma unroll
        for (int j = 0; j < 2; ++j)
          acc[i][j] = __builtin_amdgcn_mfma_f32_16x16x32_bf16(
              afr[i], bfr[ks][j], acc[i][j], 0, 0, 0);
    }
  };

  LOAD(0);
  STORE(0);
  __syncthreads();

  for (int t = 0; t < NT; t += 2) {
    if (t + 1 < NT) LOAD(t + 1);
    COMPUTE(0, t);
    if (t + 1 < NT) STORE(1);
    __syncthreads();
    if (t + 1 < NT) {
      if (t + 2 < NT) LOAD(t + 2);
      COMPUTE(1, t + 1);
      if (t + 2 < NT) STORE(0);
      __syncthreads();
    }
  }

  // epilogue: relu + store (C layout: row = (lane>>4)*4 + r, col = lane&15)
#pragma unroll
  for (int i = 0; i < 2; ++i) {
#pragma unroll
    for (int j = 0; j < 2; ++j) {
#pragma unroll
      for (int r = 0; r < 4; ++r) {
        float v = acc[i][j][r];
        v = v > 0.f ? v : 0.f;
        const long row = gm0 + i * 16 + ((lane >> 4) << 2) + r;
        const int  col = w * 32 + j * 16 + (lane & 15);
        if (WRITE_BF16) ((short*)out_)[row * DD + col] = f2bf(v);
        else            ((float*)out_)[row * DD + col] = v;
      }
    }
  }
}

// ---------------------------------------------------------------------------
extern "C" void kernel_launch(void* const* d_in, const int* in_sizes, int n_in,
                              void* d_out, int out_size, void* d_ws, size_t ws_size,
                              hipStream_t stream)
{
  const float* A  = (const float*)d_in[0];   // [16384][16384]
  const float* X  = (const float*)d_in[1];   // [16384][128]
  const float* W0 = (const float*)d_in[2];   // [128][128]
  const float* W1 = (const float*)d_in[3];   // [128][128]

  short* Tf = (short*)d_ws;                  // bf16 fragment-major T (4 MB)
  short* H1 = Tf + (size_t)DD * NN;          // bf16 [16384][128] post-relu H1

  // layer 0: T0 = X @ W0 ; H1 = relu(A @ T0)
  small_gemm<0><<<NN / 16, 256, 0, stream>>>(X, W0, Tf);
  agg_kernel<1><<<NN / BM, 256, 0, stream>>>(A, Tf, H1);
  // layer 1: T1 = H1 @ W1 ; out = relu(A @ T1)
  small_gemm<1><<<NN / 16, 256, 0, stream>>>(H1, W1, Tf);
  agg_kernel<0><<<NN / BM, 256, 0, stream>>>(A, Tf, d_out);
}